// Round 3
// baseline (282.648 us; speedup 1.0000x reference)
//
#include <hip/hip_runtime.h>

typedef unsigned short u16;
typedef short short8 __attribute__((ext_vector_type(8)));
typedef float floatx4 __attribute__((ext_vector_type(4)));

#define MFMA16(a, b, c) __builtin_amdgcn_mfma_f32_16x16x32_bf16((a), (b), (c), 0, 0, 0)

// ---- scratch byte offsets (all 256-aligned) ----
#define QW_OFF    0u         // float[4096]   s0*(A0-B0)
#define PW_OFF    16384u     // float[4096]   s0*B0
#define T0_OFF    32768u     // float[64]
#define W1F_OFF   33024u     // bf16[4096]
#define B1F_OFF   41216u     // float[64]
#define W2F_OFF   41472u     // bf16[8192]
#define B2F_OFF   57856u     // float[128]
#define WA0F_OFF  58368u     // bf16[8192]
#define BAF_OFF   74752u     // float[64]
#define WA1F_OFF  75008u     // float[64]
#define BA1F_OFF  75264u     // float[1]
#define WSCF_OFF  75520u     // float[8192]
#define TSC_OFF   108288u    // float[128]
#define P_OFF     108800u    // float[32*128*64]
#define Q_OFF     1157376u   // float[32*128*64]
#define SC_OFF    2205952u   // float[32*128*128]
#define WS_TOTAL  4303104u

// Static device scratch: independent of the (unknown-size) harness d_ws.
// Fully rewritten by k_fold/k_pre on every call before k_main reads it.
__device__ __align__(256) char g_ws[WS_TOTAL];

#define LD0 72    // padded row stride (bf16) for 64-channel activations
#define LD2 136   // padded row stride (bf16) for 128-channel activations

__device__ __forceinline__ float bf2f(u16 u) {
  union { unsigned int i; float f; } v; v.i = ((unsigned int)u) << 16; return v.f;
}
__device__ __forceinline__ u16 f2bf(float f) {
  union { float f; unsigned int i; } v; v.f = f;
  unsigned int u = v.i;
  return (u16)((u + 0x7FFFu + ((u >> 16) & 1u)) >> 16);
}

// ------------------------------------------------------------------
// Kernel A: fold BN into weights.  1 block x 256 threads.  FP32 inputs.
// ------------------------------------------------------------------
__global__ void k_fold(
    const float* __restrict__ w0, const float* __restrict__ g0, const float* __restrict__ b0, const float* __restrict__ m0, const float* __restrict__ v0,
    const float* __restrict__ w1, const float* __restrict__ g1, const float* __restrict__ b1, const float* __restrict__ m1, const float* __restrict__ v1,
    const float* __restrict__ w2, const float* __restrict__ g2, const float* __restrict__ b2, const float* __restrict__ m2, const float* __restrict__ v2,
    const float* __restrict__ wa0, const float* __restrict__ ga, const float* __restrict__ ba, const float* __restrict__ ma, const float* __restrict__ va,
    const float* __restrict__ wa1, const float* __restrict__ ba1,
    const float* __restrict__ wsc, const float* __restrict__ gsc, const float* __restrict__ bsc, const float* __restrict__ msc, const float* __restrict__ vsc)
{
  __shared__ float s0[64], t0s[64], s1[64], t1s[64], sa[64], tas[64];
  __shared__ float s2[128], t2s[128], ssc[128], tscs[128];
  const int t = threadIdx.x;
  if (t < 64) {
    float s;
    s = g0[t] * rsqrtf(v0[t] + 1e-5f); s0[t] = s; t0s[t] = b0[t] - m0[t] * s;
    s = g1[t] * rsqrtf(v1[t] + 1e-5f); s1[t] = s; t1s[t] = b1[t] - m1[t] * s;
    s = ga[t] * rsqrtf(va[t] + 1e-5f); sa[t] = s; tas[t] = ba[t] - ma[t] * s;
  }
  if (t < 128) {
    float s;
    s = g2[t] * rsqrtf(v2[t] + 1e-5f); s2[t] = s; t2s[t] = b2[t] - m2[t] * s;
    s = gsc[t] * rsqrtf(vsc[t] + 1e-5f); ssc[t] = s; tscs[t] = bsc[t] - msc[t] * s;
  }
  __syncthreads();

  char* ws = g_ws;
  float* Qw  = (float*)(ws + QW_OFF);
  float* Pw  = (float*)(ws + PW_OFF);
  float* t0o = (float*)(ws + T0_OFF);
  u16*   W1f = (u16*)(ws + W1F_OFF);
  float* b1f = (float*)(ws + B1F_OFF);
  u16*   W2f = (u16*)(ws + W2F_OFF);
  float* b2f = (float*)(ws + B2F_OFF);
  u16*   Wa0f= (u16*)(ws + WA0F_OFF);
  float* baf = (float*)(ws + BAF_OFF);
  float* wa1f= (float*)(ws + WA1F_OFF);
  float* ba1f= (float*)(ws + BA1F_OFF);
  float* Wscf= (float*)(ws + WSCF_OFF);
  float* tscf= (float*)(ws + TSC_OFF);

  for (int i = t; i < 4096; i += 256) {
    int o = i >> 6, c = i & 63;
    float wi = w0[o * 128 + c], wj = w0[o * 128 + 64 + c];
    Qw[i] = s0[o] * (wi - wj);
    Pw[i] = s0[o] * wj;
  }
  for (int i = t; i < 4096; i += 256) { int o = i >> 6; W1f[i]  = f2bf(s1[o] * w1[i]);  }
  for (int i = t; i < 8192; i += 256) { int o = i >> 6; W2f[i]  = f2bf(s2[o] * w2[i]);  }
  for (int i = t; i < 8192; i += 256) { int o = i >> 7; Wa0f[i] = f2bf(sa[o] * wa0[i]); }
  for (int i = t; i < 8192; i += 256) { int o = i >> 6; Wscf[i] = ssc[o] * wsc[i];      }
  if (t < 64)  { t0o[t] = t0s[t]; b1f[t] = t1s[t]; baf[t] = tas[t]; wa1f[t] = wa1[t]; }
  if (t < 128) { b2f[t] = t2s[t]; tscf[t] = tscs[t]; }
  if (t == 0)  ba1f[0] = ba1[0];
}

// ------------------------------------------------------------------
// Kernel B: per (b,n) precompute  P = Pw.x, Q = Qw.x + t0, SC = Wscf.x + tsc
// grid 4096, block 256 (wave-uniform role split).  FP32 features.
// ------------------------------------------------------------------
__global__ __launch_bounds__(256) void k_pre(const float* __restrict__ feat)
{
  const int blk = blockIdx.x;
  const int b = blk >> 7, n = blk & 127;
  const int t = threadIdx.x;
  __shared__ float xs[64];
  if (t < 64) xs[t] = feat[((b << 6) + t) * 128 + n];
  __syncthreads();

  char* ws = g_ws;
  float* P   = (float*)(ws + P_OFF);
  float* Q   = (float*)(ws + Q_OFF);
  float* SCp = (float*)(ws + SC_OFF);

  const float* wr; float acc; float* dst;
  if (t < 64) {
    wr = (const float*)(ws + PW_OFF) + t * 64; acc = 0.f; dst = P + blk * 64 + t;
  } else if (t < 128) {
    int o = t - 64;
    wr = (const float*)(ws + QW_OFF) + o * 64; acc = ((const float*)(ws + T0_OFF))[o]; dst = Q + blk * 64 + o;
  } else {
    int o = t - 128;
    wr = (const float*)(ws + WSCF_OFF) + o * 64; acc = ((const float*)(ws + TSC_OFF))[o]; dst = SCp + blk * 128 + o;
  }
  #pragma unroll
  for (int c = 0; c < 64; c += 4) {
    float4 w = *(const float4*)(wr + c);
    acc += w.x * xs[c] + w.y * xs[c + 1] + w.z * xs[c + 2] + w.w * xs[c + 3];
  }
  *dst = acc;
}

// ------------------------------------------------------------------
// Kernel C: fused edge chain per (b,n).  grid 4096, block 256 (4 waves).
// LDS: bufA = H0(128x72) then H2(128x136); bufB = H1(128x72) then Aatt.
// ------------------------------------------------------------------
__global__ __launch_bounds__(256) void k_main(float* __restrict__ out)
{
  __shared__ alignas(16) u16 bufA[128 * LD2];   // 34816 B
  __shared__ alignas(16) u16 bufB[128 * LD0];   // 18432 B
  __shared__ float lgs[128];
  __shared__ float attws[128];
  __shared__ float parts[2][128];

  const int blk = blockIdx.x;
  const int b = blk >> 7, n = blk & 127;
  const int t = threadIdx.x;

  const char* ws = g_ws;
  const float* Pb  = (const float*)(ws + P_OFF);
  const float* Qb  = (const float*)(ws + Q_OFF);
  const float* SCb = (const float*)(ws + SC_OFF);
  const u16*   W1f = (const u16*)(ws + W1F_OFF);
  const float* b1f = (const float*)(ws + B1F_OFF);
  const u16*   W2f = (const u16*)(ws + W2F_OFF);
  const float* b2f = (const float*)(ws + B2F_OFF);
  const u16*   Wa0f= (const u16*)(ws + WA0F_OFF);
  const float* baf = (const float*)(ws + BAF_OFF);
  const float* wa1f= (const float*)(ws + WA1F_OFF);
  const float  ba1v= *(const float*)(ws + BA1F_OFF);

  // ---- layer 0: H0[edge][ch] = relu(Q[b,n] + P[b,j]), edge 127 = dummy ----
  {
    const int k = t >> 1, half = t & 1;
    const int j = (k < 127) ? ((k < n) ? k : (k + 1)) : n;
    const float* pr = Pb + ((b << 7) + j) * 64 + half * 32;
    const float* qr = Qb + blk * 64 + half * 32;
    u16* dst = bufA + k * LD0 + half * 32;
    #pragma unroll
    for (int i = 0; i < 32; i += 4) {
      float4 p = *(const float4*)(pr + i);
      float4 q = *(const float4*)(qr + i);
      ushort4 sv;
      sv.x = f2bf(fmaxf(q.x + p.x, 0.f));
      sv.y = f2bf(fmaxf(q.y + p.y, 0.f));
      sv.z = f2bf(fmaxf(q.z + p.z, 0.f));
      sv.w = f2bf(fmaxf(q.w + p.w, 0.f));
      *(ushort4*)(dst + i) = sv;
    }
  }
  __syncthreads();

  const int lane = t & 63, wid = t >> 6;
  const int quad = lane >> 4, l16 = lane & 15;

  // ---- GEMM1: H1(64x128) = relu(W1f(64x64) @ H0 + b1) ----
  {
    floatx4 acc[2][4];
    #pragma unroll
    for (int x = 0; x < 2; x++)
      #pragma unroll
      for (int m = 0; m < 4; m++) acc[x][m] = (floatx4)(0.f);
    #pragma unroll
    for (int ks = 0; ks < 2; ks++) {
      const int k0 = ks * 32 + quad * 8;
      short8 bf0 = *(const short8*)(bufA + (wid * 16 + l16) * LD0 + k0);
      short8 bf1 = *(const short8*)(bufA + ((wid + 4) * 16 + l16) * LD0 + k0);
      #pragma unroll
      for (int mt = 0; mt < 4; mt++) {
        short8 af = *(const short8*)(W1f + (mt * 16 + l16) * 64 + k0);
        acc[0][mt] = MFMA16(af, bf0, acc[0][mt]);
        acc[1][mt] = MFMA16(af, bf1, acc[1][mt]);
      }
    }
    #pragma unroll
    for (int x = 0; x < 2; x++) {
      const int c = (wid + 4 * x) * 16 + l16;
      #pragma unroll
      for (int mt = 0; mt < 4; mt++) {
        const int r0 = mt * 16 + quad * 4;
        float4 bb = *(const float4*)(b1f + r0);
        ushort4 sv;
        sv.x = f2bf(fmaxf(acc[x][mt][0] + bb.x, 0.f));
        sv.y = f2bf(fmaxf(acc[x][mt][1] + bb.y, 0.f));
        sv.z = f2bf(fmaxf(acc[x][mt][2] + bb.z, 0.f));
        sv.w = f2bf(fmaxf(acc[x][mt][3] + bb.w, 0.f));
        *(ushort4*)(bufB + c * LD0 + r0) = sv;
      }
    }
  }
  __syncthreads();

  // ---- GEMM2: H2(128x128) = relu(W2f(128x64) @ H1 + b2) -> bufA (H0 dead) ----
  {
    floatx4 acc[2][8];
    #pragma unroll
    for (int x = 0; x < 2; x++)
      #pragma unroll
      for (int m = 0; m < 8; m++) acc[x][m] = (floatx4)(0.f);
    #pragma unroll
    for (int ks = 0; ks < 2; ks++) {
      const int k0 = ks * 32 + quad * 8;
      short8 bf0 = *(const short8*)(bufB + (wid * 16 + l16) * LD0 + k0);
      short8 bf1 = *(const short8*)(bufB + ((wid + 4) * 16 + l16) * LD0 + k0);
      #pragma unroll
      for (int mt = 0; mt < 8; mt++) {
        short8 af = *(const short8*)(W2f + (mt * 16 + l16) * 64 + k0);
        acc[0][mt] = MFMA16(af, bf0, acc[0][mt]);
        acc[1][mt] = MFMA16(af, bf1, acc[1][mt]);
      }
    }
    #pragma unroll
    for (int x = 0; x < 2; x++) {
      const int c = (wid + 4 * x) * 16 + l16;
      #pragma unroll
      for (int mt = 0; mt < 8; mt++) {
        const int r0 = mt * 16 + quad * 4;
        float4 bb = *(const float4*)(b2f + r0);
        ushort4 sv;
        sv.x = f2bf(fmaxf(acc[x][mt][0] + bb.x, 0.f));
        sv.y = f2bf(fmaxf(acc[x][mt][1] + bb.y, 0.f));
        sv.z = f2bf(fmaxf(acc[x][mt][2] + bb.z, 0.f));
        sv.w = f2bf(fmaxf(acc[x][mt][3] + bb.w, 0.f));
        *(ushort4*)(bufA + c * LD2 + r0) = sv;
      }
    }
  }
  __syncthreads();

  // ---- GEMM3: Aatt(64x128) = relu(Wa0f(64x128) @ H2 + ba) -> bufB (H1 dead) ----
  {
    floatx4 acc[2][4];
    #pragma unroll
    for (int x = 0; x < 2; x++)
      #pragma unroll
      for (int m = 0; m < 4; m++) acc[x][m] = (floatx4)(0.f);
    #pragma unroll
    for (int ks = 0; ks < 4; ks++) {
      const int k0 = ks * 32 + quad * 8;
      short8 bf0 = *(const short8*)(bufA + (wid * 16 + l16) * LD2 + k0);
      short8 bf1 = *(const short8*)(bufA + ((wid + 4) * 16 + l16) * LD2 + k0);
      #pragma unroll
      for (int mt = 0; mt < 4; mt++) {
        short8 af = *(const short8*)(Wa0f + (mt * 16 + l16) * 128 + k0);
        acc[0][mt] = MFMA16(af, bf0, acc[0][mt]);
        acc[1][mt] = MFMA16(af, bf1, acc[1][mt]);
      }
    }
    #pragma unroll
    for (int x = 0; x < 2; x++) {
      const int c = (wid + 4 * x) * 16 + l16;
      #pragma unroll
      for (int mt = 0; mt < 4; mt++) {
        const int r0 = mt * 16 + quad * 4;
        float4 bb = *(const float4*)(baf + r0);
        ushort4 sv;
        sv.x = f2bf(fmaxf(acc[x][mt][0] + bb.x, 0.f));
        sv.y = f2bf(fmaxf(acc[x][mt][1] + bb.y, 0.f));
        sv.z = f2bf(fmaxf(acc[x][mt][2] + bb.z, 0.f));
        sv.w = f2bf(fmaxf(acc[x][mt][3] + bb.w, 0.f));
        *(ushort4*)(bufB + c * LD0 + r0) = sv;
      }
    }
  }
  __syncthreads();

  // ---- logits[k] = wa1 . Aatt[:,k] + ba1 ; edge 127 masked ----
  if (t < 128) {
    const u16* row = bufB + t * LD0;
    float acc = ba1v;
    #pragma unroll
    for (int o = 0; o < 64; o++) acc += wa1f[o] * bf2f(row[o]);
    lgs[t] = (t == 127) ? -1e30f : acc;
  }
  __syncthreads();

  // ---- softmax over 127 edges (wave 0) ----
  if (wid == 0) {
    float a0 = lgs[lane], a1 = lgs[lane + 64];
    float mx = fmaxf(a0, a1);
    #pragma unroll
    for (int off = 32; off >= 1; off >>= 1) mx = fmaxf(mx, __shfl_xor(mx, off));
    float e0 = expf(a0 - mx), e1 = expf(a1 - mx);
    float sm = e0 + e1;
    #pragma unroll
    for (int off = 32; off >= 1; off >>= 1) sm += __shfl_xor(sm, off);
    float inv = 1.f / sm;
    attws[lane]      = e0 * inv;
    attws[lane + 64] = e1 * inv;   // attw[127] = 0 naturally (exp(-1e30)=0)
  }
  __syncthreads();

  // ---- fts[c] = sum_k attw[k] * H2[c][k]  (split k over two halves) ----
  {
    const int c = t & 127, h = t >> 7;
    float acc = 0.f;
    #pragma unroll 8
    for (int k = 0; k < 64; k++)
      acc += attws[h * 64 + k] * bf2f(bufA[(h * 64 + k) * LD2 + c]);
    parts[h][c] = acc;
  }
  __syncthreads();

  // ---- out = relu(SC + fts)  (fp32 output) ----
  if (t < 128) {
    float fts = parts[0][t] + parts[1][t];
    float scv = SCb[blk * 128 + t];
    out[((b << 7) + t) * 128 + n] = fmaxf(scv + fts, 0.f);
  }
}

// ------------------------------------------------------------------
extern "C" void kernel_launch(void* const* d_in, const int* in_sizes, int n_in,
                              void* d_out, int out_size, void* d_ws, size_t ws_size,
                              hipStream_t stream)
{
  (void)d_ws; (void)ws_size; (void)in_sizes; (void)n_in; (void)out_size;
  const float* feat = (const float*)d_in[0];
  const float *w0 = (const float*)d_in[1],  *g0 = (const float*)d_in[2],  *b0 = (const float*)d_in[3],  *m0 = (const float*)d_in[4],  *v0 = (const float*)d_in[5];
  const float *w1 = (const float*)d_in[6],  *g1 = (const float*)d_in[7],  *b1 = (const float*)d_in[8],  *m1 = (const float*)d_in[9],  *v1 = (const float*)d_in[10];
  const float *w2 = (const float*)d_in[11], *g2 = (const float*)d_in[12], *b2 = (const float*)d_in[13], *m2 = (const float*)d_in[14], *v2 = (const float*)d_in[15];
  const float *wa0= (const float*)d_in[16], *ga = (const float*)d_in[17], *ba = (const float*)d_in[18], *ma = (const float*)d_in[19], *va = (const float*)d_in[20];
  const float *wa1= (const float*)d_in[21], *ba1= (const float*)d_in[22];
  const float *wsc= (const float*)d_in[23], *gsc= (const float*)d_in[24], *bsc= (const float*)d_in[25], *msc= (const float*)d_in[26], *vsc= (const float*)d_in[27];

  k_fold<<<dim3(1), dim3(256), 0, stream>>>(
      w0, g0, b0, m0, v0, w1, g1, b1, m1, v1, w2, g2, b2, m2, v2,
      wa0, ga, ba, ma, va, wa1, ba1, wsc, gsc, bsc, msc, vsc);
  k_pre<<<dim3(4096), dim3(256), 0, stream>>>(feat);
  k_main<<<dim3(4096), dim3(256), 0, stream>>>((float*)d_out);
}

// Round 4
// 263.467 us; speedup vs baseline: 1.0728x; 1.0728x over previous
//
#include <hip/hip_runtime.h>

typedef unsigned short u16;
typedef short short8 __attribute__((ext_vector_type(8)));
typedef float floatx4 __attribute__((ext_vector_type(4)));

#define MFMA16(a, b, c) __builtin_amdgcn_mfma_f32_16x16x32_bf16((a), (b), (c), 0, 0, 0)

// ---- g_ws byte offsets (256-aligned) ----
#define W1F_OFF   0u         // bf16[4096]   8192 B
#define B1F_OFF   8192u      // f32[64]      256
#define W2F_OFF   8448u      // bf16[8192]   16384
#define B2F_OFF   24832u     // f32[128]     512
#define WA0F_OFF  25344u     // bf16[8192]   16384
#define BAF_OFF   41728u     // f32[64]      256
#define WA1F_OFF  41984u     // f32[64]      256
#define BA1F_OFF  42240u     // f32[1]       (pad to 256)
#define P_OFF     42496u     // f32[32*128*64]  1048576
#define Q_OFF     1091072u   // f32[32*128*64]  1048576
#define SC_OFF    2139648u   // f32[32*128*128] 2097152
#define WS_TOTAL  4236800u

__device__ __align__(256) char g_ws[WS_TOTAL];

#define LD0 72    // u16 row stride, 64-ch activations (4*l16 bank walk -> even)
#define LD2 136   // u16 row stride, 128-ch activations

__device__ __forceinline__ float bits2f(unsigned u) {
  union { unsigned i; float f; } v; v.i = u; return v.f;
}
// round-half-up bf16 (2 VALU ops; |err| <= 0.5 ulp like RNE)
__device__ __forceinline__ u16 f2bf(float f) {
  union { float f; unsigned i; } v; v.f = f;
  return (u16)((v.i + 0x8000u) >> 16);
}

// ------------------------------------------------------------------
// k_pre: blocks 0..4095 -> per-(b,n) P/Q/SC from RAW weights (BN folded
// on the fly). Block 4096 -> fold W1/W2/Wa0 + biases for k_main.
// ------------------------------------------------------------------
__global__ __launch_bounds__(256) void k_pre(
    const float* __restrict__ feat, const float* __restrict__ w0,
    const float* __restrict__ g0, const float* __restrict__ b0, const float* __restrict__ m0, const float* __restrict__ v0,
    const float* __restrict__ w1, const float* __restrict__ g1, const float* __restrict__ b1, const float* __restrict__ m1, const float* __restrict__ v1,
    const float* __restrict__ w2, const float* __restrict__ g2, const float* __restrict__ b2, const float* __restrict__ m2, const float* __restrict__ v2,
    const float* __restrict__ wa0, const float* __restrict__ ga, const float* __restrict__ ba, const float* __restrict__ ma, const float* __restrict__ va,
    const float* __restrict__ wa1, const float* __restrict__ ba1,
    const float* __restrict__ wsc, const float* __restrict__ gsc, const float* __restrict__ bsc, const float* __restrict__ msc, const float* __restrict__ vsc)
{
  const int t = threadIdx.x;
  char* ws = g_ws;

  if (blockIdx.x == 4096) {
    // ---- fold branch: W1f/W2f/Wa0f (bf16) + biases ----
    __shared__ float fs1[64], fs2[128], fsa[64];
    if (t < 64) {
      float s;
      s = g1[t] * rsqrtf(v1[t] + 1e-5f); fs1[t] = s; ((float*)(ws + B1F_OFF))[t] = b1[t] - m1[t] * s;
      s = ga[t] * rsqrtf(va[t] + 1e-5f); fsa[t] = s; ((float*)(ws + BAF_OFF))[t] = ba[t] - ma[t] * s;
      ((float*)(ws + WA1F_OFF))[t] = wa1[t];
    }
    if (t < 128) { float s = g2[t] * rsqrtf(v2[t] + 1e-5f); fs2[t] = s; ((float*)(ws + B2F_OFF))[t] = b2[t] - m2[t] * s; }
    if (t == 0) ((float*)(ws + BA1F_OFF))[0] = ba1[0];
    __syncthreads();
    u16* W1f = (u16*)(ws + W1F_OFF);
    u16* W2f = (u16*)(ws + W2F_OFF);
    u16* Wa0f = (u16*)(ws + WA0F_OFF);
    for (int i = t; i < 4096; i += 256) W1f[i]  = f2bf(fs1[i >> 6] * w1[i]);
    for (int i = t; i < 8192; i += 256) W2f[i]  = f2bf(fs2[i >> 6] * w2[i]);
    for (int i = t; i < 8192; i += 256) Wa0f[i] = f2bf(fsa[i >> 7] * wa0[i]);
    return;
  }

  // ---- pre branch ----
  const int blk = blockIdx.x, b = blk >> 7, n = blk & 127;
  __shared__ float xs[64], s0s[64], t0s[64], sscs[128], tscs[128];
  if (t < 64) {
    xs[t] = feat[((b << 6) + t) * 128 + n];
    float s = g0[t] * rsqrtf(v0[t] + 1e-5f); s0s[t] = s; t0s[t] = b0[t] - m0[t] * s;
  } else if (t < 192) {
    int o = t - 64;
    float s = gsc[o] * rsqrtf(vsc[o] + 1e-5f); sscs[o] = s; tscs[o] = bsc[o] - msc[o] * s;
  }
  __syncthreads();

  if (t < 64) {
    // P = s0 * (B0 . x);  Q = s0 * ((A0-B0) . x) + t0   (w0 row = [A0 | B0])
    const float4* row = (const float4*)(w0 + t * 128);
    float dA = 0.f, dB = 0.f;
    #pragma unroll
    for (int c = 0; c < 16; c++) {
      float4 a = row[c], bb = row[c + 16];
      float x0 = xs[c * 4], x1 = xs[c * 4 + 1], x2 = xs[c * 4 + 2], x3 = xs[c * 4 + 3];
      dA += a.x * x0 + a.y * x1 + a.z * x2 + a.w * x3;
      dB += bb.x * x0 + bb.y * x1 + bb.z * x2 + bb.w * x3;
    }
    ((float*)(ws + P_OFF))[blk * 64 + t] = s0s[t] * dB;
    ((float*)(ws + Q_OFF))[blk * 64 + t] = s0s[t] * (dA - dB) + t0s[t];
  } else if (t < 192) {
    int o = t - 64;
    const float4* row = (const float4*)(wsc + o * 64);
    float d = 0.f;
    #pragma unroll
    for (int c = 0; c < 16; c++) {
      float4 a = row[c];
      d += a.x * xs[c * 4] + a.y * xs[c * 4 + 1] + a.z * xs[c * 4 + 2] + a.w * xs[c * 4 + 3];
    }
    ((float*)(ws + SC_OFF))[blk * 128 + o] = sscs[o] * d + tscs[o];
  }
}

// ------------------------------------------------------------------
// k_main: fused edge chain per (b,n). 4096 blocks x 256 thr (4 waves).
// LDS overlay (36.9 KB): H0[128xLD0]@0, H1[128xLD0]@18432B, then
// H2[128xLD2]@0 overwrites H0/H1 after a barrier (GEMM2 output is
// register-staged). GEMM3 never materializes: logits reduced from
// MFMA accumulators. Total LDS 39936 B -> 4 blocks/CU.
// ------------------------------------------------------------------
__global__ __launch_bounds__(256, 4) void k_main(float* __restrict__ out)
{
  __shared__ alignas(16) u16 buf[18432];     // 36864 B union
  __shared__ float lgs[128], attws[128], parts[4][128];

  const int blk = blockIdx.x, b = blk >> 7, n = blk & 127, t = threadIdx.x;
  const char* ws = g_ws;
  const float* Pb  = (const float*)(ws + P_OFF);
  const float* Qb  = (const float*)(ws + Q_OFF);
  const float* SCb = (const float*)(ws + SC_OFF);
  const u16*   W1f = (const u16*)(ws + W1F_OFF);
  const float* b1f = (const float*)(ws + B1F_OFF);
  const u16*   W2f = (const u16*)(ws + W2F_OFF);
  const float* b2f = (const float*)(ws + B2F_OFF);
  const u16*   Wa0f= (const u16*)(ws + WA0F_OFF);
  const float* baf = (const float*)(ws + BAF_OFF);
  const float* wa1f= (const float*)(ws + WA1F_OFF);
  const float  ba1v= *(const float*)(ws + BA1F_OFF);

  u16* H0 = buf;            // stride LD0
  u16* H1 = buf + 9216;     // stride LD0 (byte 18432)
  u16* H2 = buf;            // stride LD2 (after barrier 3)

  // ---- L0: H0[edge][ch] = relu(Q[b,n] + P[b,j]); edge 127 dummy ----
  {
    const int k = t >> 1, half = t & 1;
    const int j = (k < 127) ? ((k < n) ? k : (k + 1)) : n;
    const float4* pr = (const float4*)(Pb + ((b << 7) + j) * 64 + half * 32);
    const float4* qr = (const float4*)(Qb + blk * 64 + half * 32);
    u16* dst = H0 + k * LD0 + half * 32;
    #pragma unroll
    for (int i = 0; i < 8; i++) {
      float4 p = pr[i], q = qr[i];
      ushort4 sv;
      sv.x = f2bf(fmaxf(q.x + p.x, 0.f));
      sv.y = f2bf(fmaxf(q.y + p.y, 0.f));
      sv.z = f2bf(fmaxf(q.z + p.z, 0.f));
      sv.w = f2bf(fmaxf(q.w + p.w, 0.f));
      *(ushort4*)(dst + i * 4) = sv;
    }
  }
  __syncthreads();                                           // (1)

  const int lane = t & 63, wid = t >> 6, quad = lane >> 4, l16 = lane & 15;

  // ---- GEMM1: H1(64x128e) = relu(W1f @ H0 + b1) ----
  {
    floatx4 acc[2][4];
    #pragma unroll
    for (int x = 0; x < 2; x++)
      #pragma unroll
      for (int m = 0; m < 4; m++) acc[x][m] = (floatx4)(0.f);
    #pragma unroll
    for (int ks = 0; ks < 2; ks++) {
      const int k0 = ks * 32 + quad * 8;
      short8 bf0 = *(const short8*)(H0 + (wid * 16 + l16) * LD0 + k0);
      short8 bf1 = *(const short8*)(H0 + ((wid + 4) * 16 + l16) * LD0 + k0);
      #pragma unroll
      for (int mt = 0; mt < 4; mt++) {
        short8 af = *(const short8*)(W1f + (mt * 16 + l16) * 64 + k0);
        acc[0][mt] = MFMA16(af, bf0, acc[0][mt]);
        acc[1][mt] = MFMA16(af, bf1, acc[1][mt]);
      }
    }
    #pragma unroll
    for (int x = 0; x < 2; x++) {
      const int c = (wid + 4 * x) * 16 + l16;
      #pragma unroll
      for (int mt = 0; mt < 4; mt++) {
        const int r0 = mt * 16 + quad * 4;
        float4 bb = *(const float4*)(b1f + r0);
        ushort4 sv;
        sv.x = f2bf(fmaxf(acc[x][mt][0] + bb.x, 0.f));
        sv.y = f2bf(fmaxf(acc[x][mt][1] + bb.y, 0.f));
        sv.z = f2bf(fmaxf(acc[x][mt][2] + bb.z, 0.f));
        sv.w = f2bf(fmaxf(acc[x][mt][3] + bb.w, 0.f));
        *(ushort4*)(H1 + c * LD0 + r0) = sv;
      }
    }
  }
  __syncthreads();                                           // (2)

  // ---- GEMM2: H2(128x128e) = relu(W2f @ H1 + b2), register-staged ----
  {
    floatx4 acc[2][8];
    #pragma unroll
    for (int x = 0; x < 2; x++)
      #pragma unroll
      for (int m = 0; m < 8; m++) acc[x][m] = (floatx4)(0.f);
    #pragma unroll
    for (int ks = 0; ks < 2; ks++) {
      const int k0 = ks * 32 + quad * 8;
      short8 bf0 = *(const short8*)(H1 + (wid * 16 + l16) * LD0 + k0);
      short8 bf1 = *(const short8*)(H1 + ((wid + 4) * 16 + l16) * LD0 + k0);
      #pragma unroll
      for (int mt = 0; mt < 8; mt++) {
        short8 af = *(const short8*)(W2f + (mt * 16 + l16) * 64 + k0);
        acc[0][mt] = MFMA16(af, bf0, acc[0][mt]);
        acc[1][mt] = MFMA16(af, bf1, acc[1][mt]);
      }
    }
    __syncthreads();                                         // (3) all H1 reads done
    #pragma unroll
    for (int x = 0; x < 2; x++) {
      const int c = (wid + 4 * x) * 16 + l16;
      #pragma unroll
      for (int mt = 0; mt < 8; mt++) {
        const int r0 = mt * 16 + quad * 4;
        float4 bb = *(const float4*)(b2f + r0);
        ushort4 sv;
        sv.x = f2bf(fmaxf(acc[x][mt][0] + bb.x, 0.f));
        sv.y = f2bf(fmaxf(acc[x][mt][1] + bb.y, 0.f));
        sv.z = f2bf(fmaxf(acc[x][mt][2] + bb.z, 0.f));
        sv.w = f2bf(fmaxf(acc[x][mt][3] + bb.w, 0.f));
        *(ushort4*)(H2 + c * LD2 + r0) = sv;
      }
    }
  }
  __syncthreads();                                           // (4)

  // ---- GEMM3 fused with logits: no Aatt materialization ----
  {
    floatx4 acc[2][4];
    #pragma unroll
    for (int x = 0; x < 2; x++)
      #pragma unroll
      for (int m = 0; m < 4; m++) acc[x][m] = (floatx4)(0.f);
    #pragma unroll
    for (int ks = 0; ks < 4; ks++) {
      const int k0 = ks * 32 + quad * 8;
      short8 bf0 = *(const short8*)(H2 + (wid * 16 + l16) * LD2 + k0);
      short8 bf1 = *(const short8*)(H2 + ((wid + 4) * 16 + l16) * LD2 + k0);
      #pragma unroll
      for (int mt = 0; mt < 4; mt++) {
        short8 af = *(const short8*)(Wa0f + (mt * 16 + l16) * 128 + k0);
        acc[0][mt] = MFMA16(af, bf0, acc[0][mt]);
        acc[1][mt] = MFMA16(af, bf1, acc[1][mt]);
      }
    }
    float p0 = 0.f, p1 = 0.f;
    #pragma unroll
    for (int mt = 0; mt < 4; mt++) {
      const int r0 = mt * 16 + quad * 4;
      float4 wv = *(const float4*)(wa1f + r0);
      float4 bb = *(const float4*)(baf + r0);
      p0 += wv.x * fmaxf(acc[0][mt][0] + bb.x, 0.f) + wv.y * fmaxf(acc[0][mt][1] + bb.y, 0.f)
          + wv.z * fmaxf(acc[0][mt][2] + bb.z, 0.f) + wv.w * fmaxf(acc[0][mt][3] + bb.w, 0.f);
      p1 += wv.x * fmaxf(acc[1][mt][0] + bb.x, 0.f) + wv.y * fmaxf(acc[1][mt][1] + bb.y, 0.f)
          + wv.z * fmaxf(acc[1][mt][2] + bb.z, 0.f) + wv.w * fmaxf(acc[1][mt][3] + bb.w, 0.f);
    }
    // reduce over quad (lane bits 4,5)
    p0 += __shfl_xor(p0, 16); p0 += __shfl_xor(p0, 32);
    p1 += __shfl_xor(p1, 16); p1 += __shfl_xor(p1, 32);
    if (quad == 0) {
      lgs[wid * 16 + l16] = p0 + ba1v;
      const int c1 = (wid + 4) * 16 + l16;
      lgs[c1] = (c1 == 127) ? -1e30f : (p1 + ba1v);
    }
  }
  __syncthreads();                                           // (5)

  // ---- softmax over 127 edges (wave 0) ----
  if (wid == 0) {
    float a0 = lgs[lane], a1 = lgs[lane + 64];
    float mx = fmaxf(a0, a1);
    #pragma unroll
    for (int off = 32; off >= 1; off >>= 1) mx = fmaxf(mx, __shfl_xor(mx, off));
    float e0 = expf(a0 - mx), e1 = expf(a1 - mx);
    float sm = e0 + e1;
    #pragma unroll
    for (int off = 32; off >= 1; off >>= 1) sm += __shfl_xor(sm, off);
    float inv = 1.f / sm;
    attws[lane] = e0 * inv;
    attws[lane + 64] = e1 * inv;   // attw[127] = 0
  }
  __syncthreads();                                           // (6)

  // ---- fts[c] = sum_e attw[e]*H2[e][c], vectorized b128 + shuffle ----
  {
    const int chg = t & 15, eg = t >> 4;   // 8 channels x 8 edges per thread
    float fa[8];
    #pragma unroll
    for (int k = 0; k < 8; k++) fa[k] = 0.f;
    #pragma unroll
    for (int i = 0; i < 8; i++) {
      const int e = eg * 8 + i;
      const float w = attws[e];
      uint4 v = *(const uint4*)(H2 + e * LD2 + chg * 8);
      unsigned u;
      u = v.x; fa[0] += w * bits2f(u << 16); fa[1] += w * bits2f(u & 0xffff0000u);
      u = v.y; fa[2] += w * bits2f(u << 16); fa[3] += w * bits2f(u & 0xffff0000u);
      u = v.z; fa[4] += w * bits2f(u << 16); fa[5] += w * bits2f(u & 0xffff0000u);
      u = v.w; fa[6] += w * bits2f(u << 16); fa[7] += w * bits2f(u & 0xffff0000u);
    }
    #pragma unroll
    for (int k = 0; k < 8; k++) { fa[k] += __shfl_xor(fa[k], 16); fa[k] += __shfl_xor(fa[k], 32); }
    if (lane < 16) {
      #pragma unroll
      for (int k = 0; k < 8; k++) parts[wid][chg * 8 + k] = fa[k];
    }
  }
  __syncthreads();                                           // (7)

  if (t < 128) {
    float fts = parts[0][t] + parts[1][t] + parts[2][t] + parts[3][t];
    out[((b << 7) + t) * 128 + n] = fmaxf(SCb[blk * 128 + t] + fts, 0.f);
  }
}

// ------------------------------------------------------------------
extern "C" void kernel_launch(void* const* d_in, const int* in_sizes, int n_in,
                              void* d_out, int out_size, void* d_ws, size_t ws_size,
                              hipStream_t stream)
{
  (void)d_ws; (void)ws_size; (void)in_sizes; (void)n_in; (void)out_size;
  const float* feat = (const float*)d_in[0];
  const float *w0 = (const float*)d_in[1],  *g0 = (const float*)d_in[2],  *b0 = (const float*)d_in[3],  *m0 = (const float*)d_in[4],  *v0 = (const float*)d_in[5];
  const float *w1 = (const float*)d_in[6],  *g1 = (const float*)d_in[7],  *b1 = (const float*)d_in[8],  *m1 = (const float*)d_in[9],  *v1 = (const float*)d_in[10];
  const float *w2 = (const float*)d_in[11], *g2 = (const float*)d_in[12], *b2 = (const float*)d_in[13], *m2 = (const float*)d_in[14], *v2 = (const float*)d_in[15];
  const float *wa0= (const float*)d_in[16], *ga = (const float*)d_in[17], *ba = (const float*)d_in[18], *ma = (const float*)d_in[19], *va = (const float*)d_in[20];
  const float *wa1= (const float*)d_in[21], *ba1= (const float*)d_in[22];
  const float *wsc= (const float*)d_in[23], *gsc= (const float*)d_in[24], *bsc= (const float*)d_in[25], *msc= (const float*)d_in[26], *vsc= (const float*)d_in[27];

  k_pre<<<dim3(4097), dim3(256), 0, stream>>>(
      feat, w0, g0, b0, m0, v0, w1, g1, b1, m1, v1, w2, g2, b2, m2, v2,
      wa0, ga, ba, ma, va, wa1, ba1, wsc, gsc, bsc, msc, vsc);
  k_main<<<dim3(4096), dim3(256), 0, stream>>>((float*)d_out);
}

// Round 5
// 168.986 us; speedup vs baseline: 1.6726x; 1.5591x over previous
//
#include <hip/hip_runtime.h>

typedef unsigned short u16;
typedef short short8 __attribute__((ext_vector_type(8)));
typedef float floatx4 __attribute__((ext_vector_type(4)));

#define MFMA16(a, b, c) __builtin_amdgcn_mfma_f32_16x16x32_bf16((a), (b), (c), 0, 0, 0)

// ---- g_ws byte offsets (256-aligned) ----
#define W1F_OFF   0u         // bf16[4096]
#define B1F_OFF   8192u      // f32[64]
#define W2F_OFF   8448u      // bf16[8192]
#define B2F_OFF   24832u     // f32[128]
#define WA0F_OFF  25344u     // bf16[8192]
#define BAF_OFF   41728u     // f32[64]
#define WA1F_OFF  41984u     // f32[64]
#define BA1F_OFF  42240u     // f32[1]
#define P_OFF     42496u     // f32[32*128*64]
#define Q_OFF     1091072u   // f32[32*128*64]
#define SC_OFF    2139648u   // f32[32*128*128]
#define WS_TOTAL  4236800u

__device__ __align__(256) char g_ws[WS_TOTAL];

#define LD0 72    // u16 row stride (64-ch) — 16B-aligned rows
#define LD2 136   // u16 row stride (128-ch) — 16B-aligned rows

__device__ __forceinline__ float bits2f(unsigned u) {
  union { unsigned i; float f; } v; v.i = u; return v.f;
}
__device__ __forceinline__ u16 f2bf(float f) {
  union { float f; unsigned i; } v; v.f = f;
  return (u16)((v.i + 0x8000u) >> 16);
}

// ------------------------------------------------------------------
// k_pre: 513 blocks x 256.
//   blocks   0..255: P/Q for (b = blk>>3, n0 = (blk&7)*16)  [w0 staged in LDS]
//   blocks 256..511: SC  for same (b, n0)                   [wsc staged in LDS]
//   block  512:      fold W1/W2/Wa0 (bf16) + biases
// All global reads coalesced; weights broadcast-read from LDS.
// ------------------------------------------------------------------
__global__ __launch_bounds__(256) void k_pre(
    const float* __restrict__ feat, const float* __restrict__ w0,
    const float* __restrict__ g0, const float* __restrict__ b0, const float* __restrict__ m0, const float* __restrict__ v0,
    const float* __restrict__ w1, const float* __restrict__ g1, const float* __restrict__ b1, const float* __restrict__ m1, const float* __restrict__ v1,
    const float* __restrict__ w2, const float* __restrict__ g2, const float* __restrict__ b2, const float* __restrict__ m2, const float* __restrict__ v2,
    const float* __restrict__ wa0, const float* __restrict__ ga, const float* __restrict__ ba, const float* __restrict__ ma, const float* __restrict__ va,
    const float* __restrict__ wa1, const float* __restrict__ ba1,
    const float* __restrict__ wsc, const float* __restrict__ gsc, const float* __restrict__ bsc, const float* __restrict__ msc, const float* __restrict__ vsc)
{
  __shared__ float smem[9600];                 // 38400 B
  const int t = threadIdx.x;
  char* ws = g_ws;
  const int blk = blockIdx.x;

  if (blk == 512) {
    float* fs1 = smem; float* fs2 = smem + 64; float* fsa = smem + 192;
    if (t < 64) {
      float s;
      s = g1[t] * rsqrtf(v1[t] + 1e-5f); fs1[t] = s; ((float*)(ws + B1F_OFF))[t] = b1[t] - m1[t] * s;
      s = ga[t] * rsqrtf(va[t] + 1e-5f); fsa[t] = s; ((float*)(ws + BAF_OFF))[t] = ba[t] - ma[t] * s;
      ((float*)(ws + WA1F_OFF))[t] = wa1[t];
    }
    if (t < 128) { float s = g2[t] * rsqrtf(v2[t] + 1e-5f); fs2[t] = s; ((float*)(ws + B2F_OFF))[t] = b2[t] - m2[t] * s; }
    if (t == 0) ((float*)(ws + BA1F_OFF))[0] = ba1[0];
    __syncthreads();
    u16* W1f = (u16*)(ws + W1F_OFF);
    u16* W2f = (u16*)(ws + W2F_OFF);
    u16* Wa0f = (u16*)(ws + WA0F_OFF);
    for (int i = t; i < 4096; i += 256) W1f[i]  = f2bf(fs1[i >> 6] * w1[i]);
    for (int i = t; i < 8192; i += 256) W2f[i]  = f2bf(fs2[i >> 6] * w2[i]);
    for (int i = t; i < 8192; i += 256) Wa0f[i] = f2bf(fsa[i >> 7] * wa0[i]);
    return;
  }

  const int sub = blk & 255;
  const int b = sub >> 3, n0 = (sub & 7) << 4;
  float* Xs  = smem;          // [64][20] f32 — the 16 staged columns
  float* Wsm = smem + 1280;   // weights

  // stage X: 64 ch x 16 n, coalesced-ish (4 lanes x 16B contiguous per row chunk)
  {
    const int c = t >> 2, j = (t & 3) << 2;
    *(float4*)(Xs + c * 20 + j) = *(const float4*)(feat + b * 8192 + c * 128 + n0 + j);
  }

  if (blk < 256) {
    // ---- P/Q branch: stage w0 (64x128) at stride 129 ----
    #pragma unroll
    for (int r = 0; r < 8; r++) {
      const int i = (r * 256 + t) * 4;
      float4 v = *(const float4*)(w0 + i);
      const int o = i >> 7, c = i & 127;
      float* d = Wsm + o * 129 + c;
      d[0] = v.x; d[1] = v.y; d[2] = v.z; d[3] = v.w;
    }
    __syncthreads();
    const int o = t >> 2, nb = (t & 3) << 2;
    const float s  = g0[o] * rsqrtf(v0[o] + 1e-5f);
    const float tt = b0[o] - m0[o] * s;
    const float* wr = Wsm + o * 129;
    float dA0=0.f,dA1=0.f,dA2=0.f,dA3=0.f,dB0=0.f,dB1=0.f,dB2=0.f,dB3=0.f;
    #pragma unroll
    for (int c = 0; c < 64; c++) {
      const float a = wr[c], e = wr[64 + c];
      const float4 x = *(const float4*)(Xs + c * 20 + nb);
      dA0 += a * x.x; dA1 += a * x.y; dA2 += a * x.z; dA3 += a * x.w;
      dB0 += e * x.x; dB1 += e * x.y; dB2 += e * x.z; dB3 += e * x.w;
    }
    float* Pp = (float*)(ws + P_OFF) + (b * 128 + n0 + nb) * 64 + o;
    float* Qp = (float*)(ws + Q_OFF) + (b * 128 + n0 + nb) * 64 + o;
    Pp[0]   = s * dB0; Pp[64]  = s * dB1; Pp[128] = s * dB2; Pp[192] = s * dB3;
    Qp[0]   = s * (dA0 - dB0) + tt; Qp[64]  = s * (dA1 - dB1) + tt;
    Qp[128] = s * (dA2 - dB2) + tt; Qp[192] = s * (dA3 - dB3) + tt;
  } else {
    // ---- SC branch: stage wsc (128x64) at stride 65 ----
    #pragma unroll
    for (int r = 0; r < 8; r++) {
      const int i = (r * 256 + t) * 4;
      float4 v = *(const float4*)(wsc + i);
      const int o = i >> 6, c = i & 63;
      float* d = Wsm + o * 65 + c;
      d[0] = v.x; d[1] = v.y; d[2] = v.z; d[3] = v.w;
    }
    __syncthreads();
    const int o = t & 127, h = (t >> 7) << 3;  // n offset 0 or 8
    const float s  = gsc[o] * rsqrtf(vsc[o] + 1e-5f);
    const float tt = bsc[o] - msc[o] * s;
    const float* wr = Wsm + o * 65;
    float d0=0.f,d1=0.f,d2=0.f,d3=0.f,d4=0.f,d5=0.f,d6=0.f,d7=0.f;
    #pragma unroll
    for (int c = 0; c < 64; c++) {
      const float a = wr[c];
      const float4 x0 = *(const float4*)(Xs + c * 20 + h);
      const float4 x1 = *(const float4*)(Xs + c * 20 + h + 4);
      d0 += a * x0.x; d1 += a * x0.y; d2 += a * x0.z; d3 += a * x0.w;
      d4 += a * x1.x; d5 += a * x1.y; d6 += a * x1.z; d7 += a * x1.w;
    }
    float* SCp = (float*)(ws + SC_OFF) + (b * 128 + n0 + h) * 128 + o;
    SCp[0]   = s * d0 + tt; SCp[128] = s * d1 + tt; SCp[256] = s * d2 + tt; SCp[384] = s * d3 + tt;
    SCp[512] = s * d4 + tt; SCp[640] = s * d5 + tt; SCp[768] = s * d6 + tt; SCp[896] = s * d7 + tt;
  }
}

// ------------------------------------------------------------------
// k_main: fused edge chain per (b,n). 4096 blocks x 256 thr (4 waves).
// M-split MFMA: each wave owns its M-rows (2-4 hoisted A-fragments),
// reads all 8 edge-tiles from LDS. LDS 39.4 KB -> 4 blocks/CU.
// ------------------------------------------------------------------
__global__ __launch_bounds__(256, 4) void k_main(float* __restrict__ out)
{
  __shared__ alignas(16) u16 buf[18432];     // 36864 B: H0@0, H1@9216(u16); H2 overlays @0 (stride 136)
  __shared__ float parts[4][128];
  __shared__ float attws[128];

  const int blk = blockIdx.x, b = blk >> 7, n = blk & 127, t = threadIdx.x;
  const char* ws = g_ws;
  const float* Pb  = (const float*)(ws + P_OFF);
  const float* Qb  = (const float*)(ws + Q_OFF);
  const float* SCb = (const float*)(ws + SC_OFF);
  const u16*   W1f = (const u16*)(ws + W1F_OFF);
  const float* b1f = (const float*)(ws + B1F_OFF);
  const u16*   W2f = (const u16*)(ws + W2F_OFF);
  const float* b2f = (const float*)(ws + B2F_OFF);
  const u16*   Wa0f= (const u16*)(ws + WA0F_OFF);
  const float* baf = (const float*)(ws + BAF_OFF);
  const float* wa1f= (const float*)(ws + WA1F_OFF);
  const float  ba1v= *(const float*)(ws + BA1F_OFF);

  u16* H0 = buf;
  u16* H1 = buf + 9216;
  u16* H2 = buf;            // after barrier (3)

  const int lane = t & 63, wid = t >> 6, quad = lane >> 4, l16 = lane & 15;
  const int koff = quad * 8;

  // hoistable A-fragments (no LDS dependence — long-latency loads up front)
  const short8 a1w0 = *(const short8*)(W1f + (wid * 16 + l16) * 64 + koff);
  const short8 a1w1 = *(const short8*)(W1f + (wid * 16 + l16) * 64 + 32 + koff);
  const short8 a2w00 = *(const short8*)(W2f + (wid * 32 + l16) * 64 + koff);
  const short8 a2w01 = *(const short8*)(W2f + (wid * 32 + l16) * 64 + 32 + koff);
  const short8 a2w10 = *(const short8*)(W2f + (wid * 32 + 16 + l16) * 64 + koff);
  const short8 a2w11 = *(const short8*)(W2f + (wid * 32 + 16 + l16) * 64 + 32 + koff);

  // ---- L0: H0[edge][ch] = relu(Q[b,n] + P[b,j]); edge 127 dummy ----
  {
    const int k = t >> 1, half = t & 1;
    const int j = (k < 127) ? ((k < n) ? k : (k + 1)) : n;
    const float4* pr = (const float4*)(Pb + ((b << 7) + j) * 64 + half * 32);
    const float4* qr = (const float4*)(Qb + blk * 64 + half * 32);
    u16* dst = H0 + k * LD0 + half * 32;
    #pragma unroll
    for (int i = 0; i < 8; i++) {
      float4 p = pr[i], q = qr[i];
      ushort4 sv;
      sv.x = f2bf(fmaxf(q.x + p.x, 0.f));
      sv.y = f2bf(fmaxf(q.y + p.y, 0.f));
      sv.z = f2bf(fmaxf(q.z + p.z, 0.f));
      sv.w = f2bf(fmaxf(q.w + p.w, 0.f));
      *(ushort4*)(dst + i * 4) = sv;
    }
  }
  __syncthreads();                                           // (1)

  // ---- GEMM1: wave owns rows wid*16..+15 of H1 ----
  {
    floatx4 acc[8];
    #pragma unroll
    for (int et = 0; et < 8; et++) acc[et] = (floatx4)(0.f);
    #pragma unroll
    for (int et = 0; et < 8; et++) {
      const u16* br = H0 + (et * 16 + l16) * LD0 + koff;
      short8 bf0 = *(const short8*)(br);
      short8 bf1 = *(const short8*)(br + 32);
      acc[et] = MFMA16(a1w0, bf0, acc[et]);
      acc[et] = MFMA16(a1w1, bf1, acc[et]);
    }
    const int r0 = wid * 16 + quad * 4;
    const float4 bb = *(const float4*)(b1f + r0);
    #pragma unroll
    for (int et = 0; et < 8; et++) {
      ushort4 sv;
      sv.x = f2bf(fmaxf(acc[et][0] + bb.x, 0.f));
      sv.y = f2bf(fmaxf(acc[et][1] + bb.y, 0.f));
      sv.z = f2bf(fmaxf(acc[et][2] + bb.z, 0.f));
      sv.w = f2bf(fmaxf(acc[et][3] + bb.w, 0.f));
      *(ushort4*)(H1 + (et * 16 + l16) * LD0 + r0) = sv;
    }
  }
  __syncthreads();                                           // (2)

  // ---- GEMM2: wave owns rows wid*32..+31 of H2; register-staged ----
  {
    floatx4 acc[2][8];
    #pragma unroll
    for (int m = 0; m < 2; m++)
      #pragma unroll
      for (int et = 0; et < 8; et++) acc[m][et] = (floatx4)(0.f);
    #pragma unroll
    for (int et = 0; et < 8; et++) {
      const u16* br = H1 + (et * 16 + l16) * LD0 + koff;
      short8 bf0 = *(const short8*)(br);
      short8 bf1 = *(const short8*)(br + 32);
      acc[0][et] = MFMA16(a2w00, bf0, acc[0][et]);
      acc[0][et] = MFMA16(a2w01, bf1, acc[0][et]);
      acc[1][et] = MFMA16(a2w10, bf0, acc[1][et]);
      acc[1][et] = MFMA16(a2w11, bf1, acc[1][et]);
    }
    __syncthreads();                                         // (3) H1 reads done
    #pragma unroll
    for (int m = 0; m < 2; m++) {
      const int r0 = wid * 32 + m * 16 + quad * 4;
      const float4 bb = *(const float4*)(b2f + r0);
      #pragma unroll
      for (int et = 0; et < 8; et++) {
        ushort4 sv;
        sv.x = f2bf(fmaxf(acc[m][et][0] + bb.x, 0.f));
        sv.y = f2bf(fmaxf(acc[m][et][1] + bb.y, 0.f));
        sv.z = f2bf(fmaxf(acc[m][et][2] + bb.z, 0.f));
        sv.w = f2bf(fmaxf(acc[m][et][3] + bb.w, 0.f));
        *(ushort4*)(H2 + (et * 16 + l16) * LD2 + r0) = sv;
      }
    }
  }
  __syncthreads();                                           // (4)

  // ---- GEMM3 + logits: wave owns att-rows wid*16..+15 ----
  {
    short8 a3[4];
    #pragma unroll
    for (int ks = 0; ks < 4; ks++)
      a3[ks] = *(const short8*)(Wa0f + (wid * 16 + l16) * 128 + ks * 32 + koff);
    floatx4 acc[8];
    #pragma unroll
    for (int et = 0; et < 8; et++) acc[et] = (floatx4)(0.f);
    #pragma unroll
    for (int et = 0; et < 8; et++) {
      const u16* br = H2 + (et * 16 + l16) * LD2 + koff;
      #pragma unroll
      for (int ks = 0; ks < 4; ks++) {
        short8 bf = *(const short8*)(br + ks * 32);
        acc[et] = MFMA16(a3[ks], bf, acc[et]);
      }
    }
    const int r0 = wid * 16 + quad * 4;
    const float4 wv = *(const float4*)(wa1f + r0);
    const float4 bb = *(const float4*)(baf + r0);
    #pragma unroll
    for (int et = 0; et < 8; et++) {
      float p = wv.x * fmaxf(acc[et][0] + bb.x, 0.f) + wv.y * fmaxf(acc[et][1] + bb.y, 0.f)
              + wv.z * fmaxf(acc[et][2] + bb.z, 0.f) + wv.w * fmaxf(acc[et][3] + bb.w, 0.f);
      p += __shfl_xor(p, 16); p += __shfl_xor(p, 32);
      if (quad == 0) parts[wid][et * 16 + l16] = p;
    }
  }
  __syncthreads();                                           // (5)

  // ---- softmax over 127 edges (wave 0) ----
  if (wid == 0) {
    float a0 = parts[0][lane] + parts[1][lane] + parts[2][lane] + parts[3][lane] + ba1v;
    float a1 = (lane == 63) ? -1e30f
             : (parts[0][lane + 64] + parts[1][lane + 64] + parts[2][lane + 64] + parts[3][lane + 64] + ba1v);
    float mx = fmaxf(a0, a1);
    #pragma unroll
    for (int off = 32; off >= 1; off >>= 1) mx = fmaxf(mx, __shfl_xor(mx, off));
    float e0 = expf(a0 - mx), e1 = expf(a1 - mx);
    float sm = e0 + e1;
    #pragma unroll
    for (int off = 32; off >= 1; off >>= 1) sm += __shfl_xor(sm, off);
    float inv = 1.f / sm;
    attws[lane] = e0 * inv;
    attws[lane + 64] = e1 * inv;   // attw[127] = 0
  }
  __syncthreads();                                           // (6)

  // ---- fts[c] = sum_e attw[e]*H2[e][c] ----
  {
    const int chg = t & 15, eg = t >> 4;   // 8 ch x 8 edges per thread
    float fa[8];
    #pragma unroll
    for (int k = 0; k < 8; k++) fa[k] = 0.f;
    #pragma unroll
    for (int i = 0; i < 8; i++) {
      const int e = eg * 8 + i;
      const float w = attws[e];
      uint4 v = *(const uint4*)(H2 + e * LD2 + chg * 8);
      unsigned u;
      u = v.x; fa[0] += w * bits2f(u << 16); fa[1] += w * bits2f(u & 0xffff0000u);
      u = v.y; fa[2] += w * bits2f(u << 16); fa[3] += w * bits2f(u & 0xffff0000u);
      u = v.z; fa[4] += w * bits2f(u << 16); fa[5] += w * bits2f(u & 0xffff0000u);
      u = v.w; fa[6] += w * bits2f(u << 16); fa[7] += w * bits2f(u & 0xffff0000u);
    }
    #pragma unroll
    for (int k = 0; k < 8; k++) { fa[k] += __shfl_xor(fa[k], 16); fa[k] += __shfl_xor(fa[k], 32); }
    if (lane < 16) {
      #pragma unroll
      for (int k = 0; k < 8; k++) parts[wid][chg * 8 + k] = fa[k];
    }
  }
  __syncthreads();                                           // (7)

  if (t < 128) {
    float fts = parts[0][t] + parts[1][t] + parts[2][t] + parts[3][t];
    out[((b << 7) + t) * 128 + n] = fmaxf(SCb[blk * 128 + t] + fts, 0.f);
  }
}

// ------------------------------------------------------------------
extern "C" void kernel_launch(void* const* d_in, const int* in_sizes, int n_in,
                              void* d_out, int out_size, void* d_ws, size_t ws_size,
                              hipStream_t stream)
{
  (void)d_ws; (void)ws_size; (void)in_sizes; (void)n_in; (void)out_size;
  const float* feat = (const float*)d_in[0];
  const float *w0 = (const float*)d_in[1],  *g0 = (const float*)d_in[2],  *b0 = (const float*)d_in[3],  *m0 = (const float*)d_in[4],  *v0 = (const float*)d_in[5];
  const float *w1 = (const float*)d_in[6],  *g1 = (const float*)d_in[7],  *b1 = (const float*)d_in[8],  *m1 = (const float*)d_in[9],  *v1 = (const float*)d_in[10];
  const float *w2 = (const float*)d_in[11], *g2 = (const float*)d_in[12], *b2 = (const float*)d_in[13], *m2 = (const float*)d_in[14], *v2 = (const float*)d_in[15];
  const float *wa0= (const float*)d_in[16], *ga = (const float*)d_in[17], *ba = (const float*)d_in[18], *ma = (const float*)d_in[19], *va = (const float*)d_in[20];
  const float *wa1= (const float*)d_in[21], *ba1= (const float*)d_in[22];
  const float *wsc= (const float*)d_in[23], *gsc= (const float*)d_in[24], *bsc= (const float*)d_in[25], *msc= (const float*)d_in[26], *vsc= (const float*)d_in[27];

  k_pre<<<dim3(513), dim3(256), 0, stream>>>(
      feat, w0, g0, b0, m0, v0, w1, g1, b1, m1, v1, w2, g2, b2, m2, v2,
      wa0, ga, ba, ma, va, wa1, ba1, wsc, gsc, bsc, msc, vsc);
  k_main<<<dim3(4096), dim3(256), 0, stream>>>((float*)d_out);
}